// Round 5
// baseline (803.742 us; speedup 1.0000x reference)
//
#include <hip/hip_runtime.h>
#include <hip/hip_bf16.h>
#include <math.h>

#define B_    8
#define SEQ_  4096
#define CIN_  7
#define DM_   512
#define NL_   4
#define PL_   16
#define NP_   256
#define NS_   16
#define DC_   4
#define DI_   1024
#define DTR_  32
#define CD_   64
#define PRED_ 96
#define TOK_  (B_*NP_)   // 2048
#define EPS_  1e-5f
#define CL_   16         // scan chunk length
#define NCH_  (NP_/CL_)  // 16 chunks

typedef unsigned short u16;
typedef __attribute__((ext_vector_type(8))) short short8;
typedef __attribute__((ext_vector_type(4))) float floatx4;

__device__ __forceinline__ float silu_f(float x){ return x / (1.f + __expf(-x)); }
__device__ __forceinline__ float softplus_f(float x){ return x > 20.f ? x : log1pf(__expf(x)); }
__device__ __forceinline__ u16 f2bf(float f){
  union { __hip_bfloat16 h; u16 u; } cv; cv.h = __float2bfloat16(f); return cv.u;
}
#define GLDS16(g, l) __builtin_amdgcn_global_load_lds( \
    (const __attribute__((address_space(1))) void*)(g), \
    (__attribute__((address_space(3))) void*)(l), 16, 0, 0)

// ---------------- LN over CIN=7 (input) ----------------
__global__ void ln7_kernel(const float* __restrict__ x, const float* __restrict__ g,
                           const float* __restrict__ b, float* __restrict__ o){
  int i = blockIdx.x*256 + threadIdx.x; // over B*SEQ
  if (i >= B_*SEQ_) return;
  float v[CIN_]; float m = 0.f;
  #pragma unroll
  for (int c=0;c<CIN_;c++){ v[c]=x[i*CIN_+c]; m+=v[c]; }
  m *= (1.f/CIN_);
  float var = 0.f;
  #pragma unroll
  for (int c=0;c<CIN_;c++){ float d=v[c]-m; var+=d*d; }
  var *= (1.f/CIN_);
  float r = rsqrtf(var + EPS_);
  #pragma unroll
  for (int c=0;c<CIN_;c++) o[i*CIN_+c] = (v[c]-m)*r*g[c]+b[c];
}

// ---------------- patch embed ----------------
__global__ __launch_bounds__(256) void embed_kernel(const float* __restrict__ xln,
    const float* __restrict__ peW, const float* __restrict__ peb, float* __restrict__ h){
  __shared__ float sp[112];
  int bn = blockIdx.x;            // b*256 + n
  int b = bn >> 8, n = bn & 255;
  int tid = threadIdx.x;
  if (tid < 112){
    int c = tid >> 4, p = tid & 15;
    sp[tid] = xln[((size_t)b*SEQ_ + n*PL_ + p)*CIN_ + c];
  }
  __syncthreads();
  #pragma unroll
  for (int half = 0; half < 2; half++){
    int d = tid + half*256;
    float acc = peb[d];
    const float* w = peW + d*112;
    #pragma unroll 14
    for (int k = 0; k < 112; k++) acc += sp[k]*w[k];
    h[(size_t)bn*DM_ + d] = acc;
  }
}

// ---------------- LN over DM=512 (fp32 out + bf16 out) ----------------
__global__ __launch_bounds__(256) void ln512_kernel(const float* __restrict__ in,
    const float* __restrict__ g, const float* __restrict__ b,
    float* __restrict__ out, u16* __restrict__ outb){
  __shared__ float red[256];
  int t = blockIdx.x, tid = threadIdx.x;
  float v0 = in[(size_t)t*DM_+tid], v1 = in[(size_t)t*DM_+tid+256];
  red[tid] = v0+v1; __syncthreads();
  for (int s=128;s>0;s>>=1){ if (tid<s) red[tid]+=red[tid+s]; __syncthreads(); }
  float m = red[0] * (1.f/DM_); __syncthreads();
  float d0 = v0-m, d1 = v1-m;
  red[tid] = d0*d0+d1*d1; __syncthreads();
  for (int s=128;s>0;s>>=1){ if (tid<s) red[tid]+=red[tid+s]; __syncthreads(); }
  float r = rsqrtf(red[0]*(1.f/DM_) + EPS_);
  float o0 = d0*r*g[tid]+b[tid];
  float o1 = d1*r*g[tid+256]+b[tid+256];
  out[(size_t)t*DM_+tid]     = o0;
  out[(size_t)t*DM_+tid+256] = o1;
  outb[(size_t)t*DM_+tid]     = f2bf(o0);
  outb[(size_t)t*DM_+tid+256] = f2bf(o1);
}

// ---------------- bf16 MFMA NT GEMM: C[M,N](f32) = A[M,K]*B[N,K]^T ----------------
// BK=64. global_load_lds(16B) staging with XOR seg swizzle.
template<int BM, int BN, bool ACC>
__global__ __launch_bounds__(256) void gemm_bf16(const u16* __restrict__ A,
    const u16* __restrict__ Bw, float* __restrict__ C, int K, int lda, int ldb, int ldc){
  constexpr int MI = BM/32, NI = BN/32;
  __shared__ __align__(16) u16 As[BM*64];
  __shared__ __align__(16) u16 Bs[BN*64];
  int tid = threadIdx.x;
  int wave = __builtin_amdgcn_readfirstlane(tid>>6);
  int lane = tid&63;
  int wm = wave>>1, wn = wave&1;
  int quad = lane>>4, l16 = lane&15;
  int bm = blockIdx.y*BM, bn = blockIdx.x*BN;
  int r8 = lane>>3, sseg = lane&7;
  int gseg = sseg ^ r8;                  // global k-seg this lane fetches
  floatx4 acc[MI][NI] = {};
  for (int k0 = 0; k0 < K; k0 += 64){
    #pragma unroll
    for (int r = 0; r < BM/32; r++){
      int rowb = (r*4 + wave)*8;
      const u16* gp = A + (size_t)(bm + rowb + r8)*lda + k0 + gseg*8;
      GLDS16(gp, &As[rowb*64]);
    }
    #pragma unroll
    for (int r = 0; r < BN/32; r++){
      int rowb = (r*4 + wave)*8;
      const u16* gp = Bw + (size_t)(bn + rowb + r8)*ldb + k0 + gseg*8;
      GLDS16(gp, &Bs[rowb*64]);
    }
    __syncthreads();
    #pragma unroll
    for (int kh = 0; kh < 2; kh++){
      short8 af[MI], bfr[NI];
      #pragma unroll
      for (int i = 0; i < MI; i++){
        int row = wm*(BM/2)+i*16+l16;
        af[i] = *(short8*)&As[row*64 + (((kh*4+quad)^(row&7))*8)];
      }
      #pragma unroll
      for (int j = 0; j < NI; j++){
        int row = wn*(BN/2)+j*16+l16;
        bfr[j] = *(short8*)&Bs[row*64 + (((kh*4+quad)^(row&7))*8)];
      }
      #pragma unroll
      for (int i = 0; i < MI; i++)
        #pragma unroll
        for (int j = 0; j < NI; j++)
          acc[i][j] = __builtin_amdgcn_mfma_f32_16x16x32_bf16(af[i], bfr[j], acc[i][j], 0, 0, 0);
    }
    __syncthreads();
  }
  #pragma unroll
  for (int i = 0; i < MI; i++){
    #pragma unroll
    for (int j = 0; j < NI; j++){
      #pragma unroll
      for (int r = 0; r < 4; r++){
        int m  = bm + wm*(BM/2) + i*16 + quad*4 + r;
        int nn = bn + wn*(BN/2) + j*16 + l16;
        if (ACC) C[(size_t)m*ldc+nn] += acc[i][j][r];
        else     C[(size_t)m*ldc+nn]  = acc[i][j][r];
      }
    }
  }
}

// ---------------- causal depthwise conv (DC=4) + bias + silu, float4 over channels ----------------
__global__ void conv_silu_kernel(const float* __restrict__ xz, const float* __restrict__ cW,
                                 const float* __restrict__ cb, float* __restrict__ xc){
  int idx = blockIdx.x*256 + threadIdx.x;   // over TOK*DI/4
  if (idx >= TOK_*DI_/4) return;
  int c4 = idx & (DI_/4 - 1); int t = idx >> 8;
  int l = t & (NP_-1);
  int c = c4*4;
  float4 acc = *(const float4*)&cb[c];
  float4 w0 = *(const float4*)&cW[(c+0)*DC_];
  float4 w1 = *(const float4*)&cW[(c+1)*DC_];
  float4 w2 = *(const float4*)&cW[(c+2)*DC_];
  float4 w3 = *(const float4*)&cW[(c+3)*DC_];
  float wa[4] = {w0.x, w0.y, w0.z, w0.w};
  float wb[4] = {w1.x, w1.y, w1.z, w1.w};
  float wc[4] = {w2.x, w2.y, w2.z, w2.w};
  float wd[4] = {w3.x, w3.y, w3.z, w3.w};
  const float* base = xz + (size_t)t*(2*DI_) + c;
  #pragma unroll
  for (int k = 0; k < DC_; k++){
    if (l - 3 + k >= 0){
      float4 xv = *(const float4*)(base + (k-3)*(2*DI_));
      acc.x += xv.x*wa[k];
      acc.y += xv.y*wb[k];
      acc.z += xv.z*wc[k];
      acc.w += xv.w*wd[k];
    }
  }
  acc.x = silu_f(acc.x); acc.y = silu_f(acc.y);
  acc.z = silu_f(acc.z); acc.w = silu_f(acc.w);
  *(float4*)&xc[(size_t)t*DI_ + c] = acc;
}

// ---------------- dbl[t,e] = sum_k xc[t,k]*W_x[e,k], LDS k-tiled ----------------
// block = 8 tokens, 4 waves (2 t each); wxT chunk [64k][64e] shared in LDS.
__global__ __launch_bounds__(256) void dbl_kernel(const float* __restrict__ xc,
    const float* __restrict__ wxT, float* __restrict__ dbl){
  __shared__ float swx[64][64];   // 16 KB [k][e]
  __shared__ float sxc[8][64];    // 2 KB  [t][k]
  int tid = threadIdx.x;
  int wave = tid >> 6, lane = tid & 63;
  int t0 = blockIdx.x*8;
  int ta = wave*2, tb = ta + 1;
  float acc0 = 0.f, acc1 = 0.f;
  for (int k0 = 0; k0 < DI_; k0 += 64){
    #pragma unroll
    for (int i = tid; i < 1024; i += 256){      // 1024 float4s = 64x64
      int r = i >> 4, cc = (i & 15)*4;
      *(float4*)&swx[r][cc] = *(const float4*)&wxT[(size_t)(k0 + r)*64 + cc];
    }
    {
      int i = tid*2;
      int t = i >> 6, k = i & 63;
      float2 v = *(const float2*)&xc[(size_t)(t0 + t)*DI_ + k0 + k];
      sxc[t][k] = v.x; sxc[t][k+1] = v.y;
    }
    __syncthreads();
    #pragma unroll 16
    for (int k = 0; k < 64; k++){
      float w = swx[k][lane];
      acc0 += sxc[ta][k]*w;
      acc1 += sxc[tb][k]*w;
    }
    __syncthreads();
  }
  dbl[(size_t)(t0 + ta)*64 + lane] = acc0;
  dbl[(size_t)(t0 + tb)*64 + lane] = acc1;
}

// ---------------- delta = softplus(dt @ W_dt^T + b_dt), 16 t per block ----------------
__global__ __launch_bounds__(256) void delta_kernel(const float* __restrict__ dbl,
    const float* __restrict__ wdtT, const float* __restrict__ bdt, float* __restrict__ delta){
  __shared__ float sdt[16][DTR_];
  int tid = threadIdx.x;
  int t0 = blockIdx.y*16;
  int d = blockIdx.x*256 + tid;
  for (int i = tid; i < 16*DTR_; i += 256){
    int t = i >> 5, r = i & 31;
    sdt[t][r] = dbl[(size_t)(t0 + t)*64 + r];
  }
  float wv[DTR_];
  #pragma unroll
  for (int r = 0; r < DTR_; r++) wv[r] = wdtT[(size_t)r*DI_ + d];
  float bb = bdt[d];
  __syncthreads();
  #pragma unroll 4
  for (int t = 0; t < 16; t++){
    float acc = bb;
    #pragma unroll
    for (int r = 0; r < DTR_; r++) acc += sdt[t][r]*wv[r];
    delta[(size_t)(t0 + t)*DI_ + d] = softplus_f(acc);
  }
}

// ---------------- chunked selective scan, d-per-lane (16 n-states in registers) ----------------
__global__ __launch_bounds__(256) void scan_part_kernel(const float* __restrict__ delta,
    const float* __restrict__ xc, const float* __restrict__ dbl,
    const float* __restrict__ Alog, float* __restrict__ hend, float* __restrict__ aprod){
  __shared__ float sBC[CL_][32];
  int tid = threadIdx.x;
  int d = blockIdx.x*256 + tid;
  int bych = blockIdx.y;               // b*NCH + ch
  int b = bych >> 4, ch = bych & (NCH_-1);
  int base = b*NP_ + ch*CL_;
  for (int i = tid; i < CL_*32; i += 256){
    int t = i >> 5, c = i & 31;
    sBC[t][c] = dbl[(size_t)(base+t)*64 + 32 + c];
  }
  float A[NS_], h[NS_], pr[NS_];
  #pragma unroll
  for (int k = 0; k < NS_; k++){
    A[k] = -__expf(Alog[(size_t)d*NS_ + k]);
    h[k] = 0.f; pr[k] = 1.f;
  }
  __syncthreads();
  #pragma unroll
  for (int t = 0; t < CL_; t++){
    int row = base + t;
    float de = delta[(size_t)row*DI_ + d];
    float xv = xc[(size_t)row*DI_ + d];
    float cde = de*xv;
    #pragma unroll
    for (int k = 0; k < NS_; k++){
      float a = __expf(de*A[k]);
      h[k] = a*h[k] + cde*sBC[t][k];
      pr[k] *= a;
    }
  }
  size_t o = ((size_t)bych*DI_ + d)*NS_;
  #pragma unroll
  for (int k = 0; k < NS_; k++){ hend[o+k] = h[k]; aprod[o+k] = pr[k]; }
}

__global__ __launch_bounds__(256) void scan_fix_kernel(const float* __restrict__ aprod,
    float* __restrict__ hend){
  int id = blockIdx.x*256 + threadIdx.x;  // over B*DI*NS = 131072
  int nd = id & (DI_*NS_ - 1);            // (d,n) packed
  int b  = id >> 14;
  float h = 0.f;
  #pragma unroll
  for (int ch = 0; ch < NCH_; ch++){
    size_t idx = (size_t)(b*NCH_ + ch)*(DI_*NS_) + nd;
    float ap = aprod[idx];
    float he = hend[idx];
    hend[idx] = h;                       // becomes h_in for this chunk
    h = ap*h + he;
  }
}

__global__ __launch_bounds__(256) void scan_final_kernel(const float* __restrict__ delta,
    const float* __restrict__ xc, const float* __restrict__ dbl,
    const float* __restrict__ xz, const float* __restrict__ Dv,
    const float* __restrict__ Alog, const float* __restrict__ hin,
    u16* __restrict__ yb){
  __shared__ float sBC[CL_][32];
  int tid = threadIdx.x;
  int d = blockIdx.x*256 + tid;
  int bych = blockIdx.y;
  int b = bych >> 4, ch = bych & (NCH_-1);
  int base = b*NP_ + ch*CL_;
  for (int i = tid; i < CL_*32; i += 256){
    int t = i >> 5, c = i & 31;
    sBC[t][c] = dbl[(size_t)(base+t)*64 + 32 + c];
  }
  float A[NS_], h[NS_];
  size_t o = ((size_t)bych*DI_ + d)*NS_;
  #pragma unroll
  for (int k = 0; k < NS_; k++){
    A[k] = -__expf(Alog[(size_t)d*NS_ + k]);
    h[k] = hin[o + k];
  }
  float Dvd = Dv[d];
  __syncthreads();
  #pragma unroll
  for (int t = 0; t < CL_; t++){
    int row = base + t;
    float de = delta[(size_t)row*DI_ + d];
    float xv = xc[(size_t)row*DI_ + d];
    float zz = xz[(size_t)row*(2*DI_) + DI_ + d];
    float cde = de*xv;
    float p = 0.f;
    #pragma unroll
    for (int k = 0; k < NS_; k++){
      float a = __expf(de*A[k]);
      h[k] = a*h[k] + cde*sBC[t][k];
      p += h[k]*sBC[t][16+k];
    }
    yb[(size_t)row*DI_ + d] = f2bf((p + xv*Dvd) * silu_f(zz));
  }
}

// ---------------- head GEMM1: 8 n per block, float4, split-k=16 ----------------
__global__ __launch_bounds__(256) void head1_kernel(const float* __restrict__ u,
    const float* __restrict__ hW1, float* __restrict__ partial){
  const int KTOT = DM_*NP_;        // 131072
  const int KLEN = KTOT/16;        // 8192
  int nb = blockIdx.x;             // 0..15 (8 n each)
  int kc = blockIdx.y;             // 0..15
  int tid = threadIdx.x;
  int lane = tid & 63, wave = tid >> 6;
  float acc[8][8] = {};            // [n][m]
  int kbase = kc*KLEN;
  for (int kk = tid*4; kk < KLEN; kk += 1024){
    int k = kbase + kk;
    float4 uv[8];
    #pragma unroll
    for (int m = 0; m < 8; m++) uv[m] = *(const float4*)&u[(size_t)m*KTOT + k];
    #pragma unroll
    for (int n = 0; n < 8; n++){
      float4 wv = *(const float4*)&hW1[(size_t)(nb*8+n)*KTOT + k];
      #pragma unroll
      for (int m = 0; m < 8; m++)
        acc[n][m] += uv[m].x*wv.x + uv[m].y*wv.y + uv[m].z*wv.z + uv[m].w*wv.w;
    }
  }
  __shared__ float red[8][4][8];   // [m][wave][n]
  #pragma unroll
  for (int m = 0; m < 8; m++){
    #pragma unroll
    for (int n = 0; n < 8; n++){
      float v = acc[n][m];
      v += __shfl_xor(v,1); v += __shfl_xor(v,2); v += __shfl_xor(v,4);
      v += __shfl_xor(v,8); v += __shfl_xor(v,16); v += __shfl_xor(v,32);
      if (lane == n) red[m][wave][n] = v;
    }
  }
  __syncthreads();
  if (tid < 64){
    int m = tid >> 3, n = tid & 7;
    float s = red[m][0][n] + red[m][1][n] + red[m][2][n] + red[m][3][n];
    partial[((size_t)kc*128 + nb*8 + n)*8 + m] = s;
  }
}

__global__ void head_combine_kernel(const float* __restrict__ partial,
    const float* __restrict__ hb1, float* __restrict__ t1){
  int idx = blockIdx.x*256 + threadIdx.x;  // n*8+m, 1024 total
  if (idx >= 128*8) return;
  int n = idx >> 3, m = idx & 7;
  float s = hb1[n];
  #pragma unroll
  for (int kc = 0; kc < 16; kc++) s += partial[((size_t)kc*128 + n)*8 + m];
  float ge = 0.5f*s*(1.f + erff(s*0.70710678118f));
  t1[m*128 + n] = ge;
}

__global__ void head2_kernel(const float* __restrict__ t1, const float* __restrict__ hW2,
                             const float* __restrict__ hb2, float* __restrict__ out){
  int idx = blockIdx.x*128 + threadIdx.x;  // 8*96
  if (idx >= B_*PRED_) return;
  int m = idx / PRED_, q = idx % PRED_;
  float s = hb2[q];
  #pragma unroll 16
  for (int k = 0; k < 2*CD_; k++) s += t1[m*128 + k]*hW2[q*128 + k];
  out[idx] = s;
}

// ---------------- prep: transposes + bf16 weight conversions ----------------
__global__ void prep_kernel(const float* __restrict__ W_dt, const float* __restrict__ W_x,
                            const float* __restrict__ W_in, const float* __restrict__ W_out,
                            float* __restrict__ wdtT, float* __restrict__ wxT,
                            u16* __restrict__ WinB, u16* __restrict__ WoutB){
  int idx = blockIdx.x*256 + threadIdx.x;
  if (idx < NL_*DTR_*DI_){
    int l = idx / (DTR_*DI_); int rem = idx % (DTR_*DI_);
    int r = rem / DI_; int d = rem % DI_;
    wdtT[idx] = W_dt[((size_t)l*DI_ + d)*DTR_ + r];
  }
  if (idx < NL_*DI_*64){
    int l = idx / (DI_*64); int rem = idx % (DI_*64);
    int k = rem / 64; int e = rem % 64;
    wxT[idx] = W_x[((size_t)l*64 + e)*DI_ + k];
  }
  if (idx < NL_*2*DI_*DM_) WinB[idx]  = f2bf(W_in[idx]);
  if (idx < NL_*DM_*DI_)   WoutB[idx] = f2bf(W_out[idx]);
}

extern "C" void kernel_launch(void* const* d_in, const int* in_sizes, int n_in,
                              void* d_out, int out_size, void* d_ws, size_t ws_size,
                              hipStream_t stream) {
  const float* x      = (const float*)d_in[0];
  const float* in_g   = (const float*)d_in[1];
  const float* in_b   = (const float*)d_in[2];
  const float* pe_W   = (const float*)d_in[3];
  const float* pe_b   = (const float*)d_in[4];
  const float* ln_g   = (const float*)d_in[5];
  const float* ln_b   = (const float*)d_in[6];
  const float* W_in   = (const float*)d_in[7];
  const float* conv_W = (const float*)d_in[8];
  const float* conv_b = (const float*)d_in[9];
  const float* W_x    = (const float*)d_in[10];
  const float* W_dt   = (const float*)d_in[11];
  const float* b_dt   = (const float*)d_in[12];
  const float* A_log  = (const float*)d_in[13];
  const float* Dskip  = (const float*)d_in[14];
  const float* W_out  = (const float*)d_in[15];
  const float* fn_g   = (const float*)d_in[16];
  const float* fn_b   = (const float*)d_in[17];
  const float* hW1    = (const float*)d_in[18];
  const float* hb1    = (const float*)d_in[19];
  const float* hW2    = (const float*)d_in[20];
  const float* hb2    = (const float*)d_in[21];

  float* ws    = (float*)d_ws;
  float* h     = ws;                    // 1,048,576 f
  float* un    = h     + 1048576;       // 1,048,576 f
  float* xz    = un    + 1048576;       // 4,194,304 f
  float* xc    = xz    + 4194304;       // 2,097,152 f
  float* dblb  = xc    + 2097152;       //   131,072 f
  float* delta = dblb  + 131072;        // 2,097,152 f
  float* y     = delta + 2097152;       // 2,097,152 f   (reused: hend/hin)
  float* wdtT  = y     + 2097152;       //   131,072 f
  float* wxT   = wdtT  + 131072;        //   262,144 f
  float* bf_rgn= wxT   + 262144;
  u16*   unb   = (u16*)bf_rgn;                  // 1,048,576 u16
  u16*   yb    = (u16*)(bf_rgn + 524288);       // 2,097,152 u16
  u16*   WinB  = (u16*)(bf_rgn + 524288 + 1048576);            // 4,194,304 u16
  u16*   WoutB = (u16*)(bf_rgn + 524288 + 1048576 + 2097152);  // 2,097,152 u16
  float* aprod = ws + 17825792;         // 2,097,152 f  (total 19,922,944 f = 79.7 MB)
  float* hend  = y;                     // [B*NCH][DI][NS]; becomes hin after pass B
  float* xln     = y;                   // prologue-only, overlays y
  float* partial = xz;                  // epilogue-only, overlays xz
  float* t1      = xz + 16384;

  prep_kernel<<<16384, 256, 0, stream>>>(W_dt, W_x, W_in, W_out, wdtT, wxT, WinB, WoutB);
  ln7_kernel<<<(B_*SEQ_+255)/256, 256, 0, stream>>>(x, in_g, in_b, xln);
  embed_kernel<<<TOK_, 256, 0, stream>>>(xln, pe_W, pe_b, h);

  for (int l = 0; l < NL_; l++){
    ln512_kernel<<<TOK_, 256, 0, stream>>>(h, ln_g + l*DM_, ln_b + l*DM_, un, unb);
    gemm_bf16<128,128,false><<<dim3(2*DI_/128, TOK_/128), 256, 0, stream>>>(
        unb, WinB + (size_t)l*2*DI_*DM_, xz, DM_, DM_, DM_, 2*DI_);
    conv_silu_kernel<<<(TOK_*DI_/4)/256, 256, 0, stream>>>(
        xz, conv_W + (size_t)l*DI_*DC_, conv_b + (size_t)l*DI_, xc);
    dbl_kernel<<<TOK_/8, 256, 0, stream>>>(xc, wxT + (size_t)l*DI_*64, dblb);
    delta_kernel<<<dim3(DI_/256, TOK_/16), 256, 0, stream>>>(
        dblb, wdtT + (size_t)l*DTR_*DI_, b_dt + (size_t)l*DI_, delta);
    scan_part_kernel<<<dim3(DI_/256, B_*NCH_), 256, 0, stream>>>(
        delta, xc, dblb, A_log + (size_t)l*DI_*NS_, hend, aprod);
    scan_fix_kernel<<<(B_*DI_*NS_)/256, 256, 0, stream>>>(aprod, hend);
    scan_final_kernel<<<dim3(DI_/256, B_*NCH_), 256, 0, stream>>>(
        delta, xc, dblb, xz, Dskip + (size_t)l*DI_, A_log + (size_t)l*DI_*NS_, hend, yb);
    gemm_bf16<64,64,true><<<dim3(DM_/64, TOK_/64), 256, 0, stream>>>(
        yb, WoutB + (size_t)l*DM_*DI_, h, DI_, DI_, DI_, DM_);
  }

  ln512_kernel<<<TOK_, 256, 0, stream>>>(h, fn_g, fn_b, un, unb);
  head1_kernel<<<dim3(16, 16), 256, 0, stream>>>(un, hW1, partial);
  head_combine_kernel<<<4, 256, 0, stream>>>(partial, hb1, t1);
  head2_kernel<<<6, 128, 0, stream>>>(t1, hW2, hb2, (float*)d_out);
}

// Round 6
// 671.653 us; speedup vs baseline: 1.1967x; 1.1967x over previous
//
#include <hip/hip_runtime.h>
#include <hip/hip_bf16.h>
#include <math.h>

#define B_    8
#define SEQ_  4096
#define CIN_  7
#define DM_   512
#define NL_   4
#define PL_   16
#define NP_   256
#define NS_   16
#define DC_   4
#define DI_   1024
#define DTR_  32
#define CD_   64
#define PRED_ 96
#define TOK_  (B_*NP_)   // 2048
#define EPS_  1e-5f
#define CL_   16         // scan chunk length
#define NCH_  (NP_/CL_)  // 16 chunks

typedef unsigned short u16;
typedef __attribute__((ext_vector_type(8))) short short8;
typedef __attribute__((ext_vector_type(4))) float floatx4;

__device__ __forceinline__ float silu_f(float x){ return x / (1.f + __expf(-x)); }
__device__ __forceinline__ float softplus_f(float x){ return x > 20.f ? x : log1pf(__expf(x)); }
__device__ __forceinline__ u16 f2bf(float f){
  union { __hip_bfloat16 h; u16 u; } cv; cv.h = __float2bfloat16(f); return cv.u;
}
#define GLDS16(g, l) __builtin_amdgcn_global_load_lds( \
    (const __attribute__((address_space(1))) void*)(g), \
    (__attribute__((address_space(3))) void*)(l), 16, 0, 0)

// ---------------- LN over CIN=7 -> bf16 patch rows [2048][128] (zero-padded 112..127) ----------------
__global__ void ln7_kernel(const float* __restrict__ x, const float* __restrict__ g,
                           const float* __restrict__ b, u16* __restrict__ xpb){
  int i = blockIdx.x*256 + threadIdx.x; // over B*SEQ
  if (i >= B_*SEQ_) return;
  float v[CIN_]; float m = 0.f;
  #pragma unroll
  for (int c=0;c<CIN_;c++){ v[c]=x[i*CIN_+c]; m+=v[c]; }
  m *= (1.f/CIN_);
  float var = 0.f;
  #pragma unroll
  for (int c=0;c<CIN_;c++){ float d=v[c]-m; var+=d*d; }
  var *= (1.f/CIN_);
  float r = rsqrtf(var + EPS_);
  int bn = i >> 4, p = i & 15;            // token, pos-in-patch
  u16* row = xpb + (size_t)bn*128;
  #pragma unroll
  for (int c=0;c<CIN_;c++) row[c*16+p] = f2bf((v[c]-m)*r*g[c]+b[c]);
  row[112+p] = 0;
}

// ---------------- LN over DM=512, wave-per-token, fp32+bf16 out ----------------
__global__ __launch_bounds__(256) void ln512_kernel(const float* __restrict__ in,
    const float* __restrict__ g, const float* __restrict__ b,
    float* __restrict__ out, u16* __restrict__ outb){
  int tid = threadIdx.x;
  int wv = tid>>6, lane = tid&63;
  int t = blockIdx.x*4 + wv;
  const float4* row = (const float4*)(in + (size_t)t*DM_);
  float4 v0 = row[lane], v1 = row[64+lane];
  float s = v0.x+v0.y+v0.z+v0.w + v1.x+v1.y+v1.z+v1.w;
  #pragma unroll
  for (int o=1;o<64;o<<=1) s += __shfl_xor(s,o);
  float m = s*(1.f/DM_);
  float d0x=v0.x-m,d0y=v0.y-m,d0z=v0.z-m,d0w=v0.w-m;
  float d1x=v1.x-m,d1y=v1.y-m,d1z=v1.z-m,d1w=v1.w-m;
  float q = d0x*d0x+d0y*d0y+d0z*d0z+d0w*d0w + d1x*d1x+d1y*d1y+d1z*d1z+d1w*d1w;
  #pragma unroll
  for (int o=1;o<64;o<<=1) q += __shfl_xor(q,o);
  float r = rsqrtf(q*(1.f/DM_) + EPS_);
  float4 g0 = ((const float4*)g)[lane], g1 = ((const float4*)g)[64+lane];
  float4 b0 = ((const float4*)b)[lane], b1 = ((const float4*)b)[64+lane];
  float4 o0 = { d0x*r*g0.x+b0.x, d0y*r*g0.y+b0.y, d0z*r*g0.z+b0.z, d0w*r*g0.w+b0.w };
  float4 o1 = { d1x*r*g1.x+b1.x, d1y*r*g1.y+b1.y, d1z*r*g1.z+b1.z, d1w*r*g1.w+b1.w };
  ((float4*)(out + (size_t)t*DM_))[lane]    = o0;
  ((float4*)(out + (size_t)t*DM_))[64+lane] = o1;
  ushort4 p0 = { f2bf(o0.x), f2bf(o0.y), f2bf(o0.z), f2bf(o0.w) };
  ushort4 p1 = { f2bf(o1.x), f2bf(o1.y), f2bf(o1.z), f2bf(o1.w) };
  ((ushort4*)(outb + (size_t)t*DM_))[lane]    = p0;
  ((ushort4*)(outb + (size_t)t*DM_))[64+lane] = p1;
}

// ---------------- bf16 MFMA NT GEMM: C[M,N](f32) = A[M,K]*B[N,K]^T (+bias) ----------------
template<int BM, int BN, bool ACC, bool BIAS>
__global__ __launch_bounds__(256) void gemm_bf16(const u16* __restrict__ A,
    const u16* __restrict__ Bw, float* __restrict__ C, const float* __restrict__ bias,
    int K, int lda, int ldb, int ldc){
  constexpr int MI = BM/32, NI = BN/32;
  __shared__ __align__(16) u16 As[BM*64];
  __shared__ __align__(16) u16 Bs[BN*64];
  int tid = threadIdx.x;
  int wave = __builtin_amdgcn_readfirstlane(tid>>6);
  int lane = tid&63;
  int wm = wave>>1, wn = wave&1;
  int quad = lane>>4, l16 = lane&15;
  int bm = blockIdx.y*BM, bn = blockIdx.x*BN;
  int r8 = lane>>3, sseg = lane&7;
  int gseg = sseg ^ r8;                  // global k-seg this lane fetches
  floatx4 acc[MI][NI] = {};
  for (int k0 = 0; k0 < K; k0 += 64){
    #pragma unroll
    for (int r = 0; r < BM/32; r++){
      int rowb = (r*4 + wave)*8;
      const u16* gp = A + (size_t)(bm + rowb + r8)*lda + k0 + gseg*8;
      GLDS16(gp, &As[rowb*64]);
    }
    #pragma unroll
    for (int r = 0; r < BN/32; r++){
      int rowb = (r*4 + wave)*8;
      const u16* gp = Bw + (size_t)(bn + rowb + r8)*ldb + k0 + gseg*8;
      GLDS16(gp, &Bs[rowb*64]);
    }
    __syncthreads();
    #pragma unroll
    for (int kh = 0; kh < 2; kh++){
      short8 af[MI], bfr[NI];
      #pragma unroll
      for (int i = 0; i < MI; i++){
        int row = wm*(BM/2)+i*16+l16;
        af[i] = *(short8*)&As[row*64 + (((kh*4+quad)^(row&7))*8)];
      }
      #pragma unroll
      for (int j = 0; j < NI; j++){
        int row = wn*(BN/2)+j*16+l16;
        bfr[j] = *(short8*)&Bs[row*64 + (((kh*4+quad)^(row&7))*8)];
      }
      #pragma unroll
      for (int i = 0; i < MI; i++)
        #pragma unroll
        for (int j = 0; j < NI; j++)
          acc[i][j] = __builtin_amdgcn_mfma_f32_16x16x32_bf16(af[i], bfr[j], acc[i][j], 0, 0, 0);
    }
    __syncthreads();
  }
  #pragma unroll
  for (int i = 0; i < MI; i++){
    #pragma unroll
    for (int j = 0; j < NI; j++){
      #pragma unroll
      for (int r = 0; r < 4; r++){
        int m  = bm + wm*(BM/2) + i*16 + quad*4 + r;
        int nn = bn + wn*(BN/2) + j*16 + l16;
        float v = acc[i][j][r];
        if (ACC) C[(size_t)m*ldc+nn] += v;
        else     C[(size_t)m*ldc+nn]  = BIAS ? v + bias[nn] : v;
      }
    }
  }
}

// ---------------- fused conv+silu -> dbl -> delta, per 8-token block ----------------
__global__ __launch_bounds__(256) void mid_kernel(
    const float* __restrict__ xz, const float* __restrict__ cW, const float* __restrict__ cb,
    const float* __restrict__ wxT, const float* __restrict__ wdtT, const float* __restrict__ bdt,
    float* __restrict__ xc, float* __restrict__ dblo, float* __restrict__ delta){
  __shared__ float sxc[8*1024];     // 32 KB
  __shared__ float swx[64*68];      // 17 KB, [e][k] transposed, pad 68
  __shared__ float sdbl[8][64];
  int tid = threadIdx.x;
  int t0 = blockIdx.x*8;
  int l0 = t0 & (NP_-1);
  // P1: conv + silu (thread = 4 channels, all 8 rows)
  int c = tid*4;
  float w0[4], w1[4], w2[4], w3[4];
  *(float4*)w0 = *(const float4*)&cW[(c+0)*DC_];
  *(float4*)w1 = *(const float4*)&cW[(c+1)*DC_];
  *(float4*)w2 = *(const float4*)&cW[(c+2)*DC_];
  *(float4*)w3 = *(const float4*)&cW[(c+3)*DC_];
  float4 bias4 = *(const float4*)&cb[c];
  #pragma unroll
  for (int r = 0; r < 8; r++){
    float4 acc = bias4;
    int l = l0 + r;
    #pragma unroll
    for (int k = 0; k < DC_; k++){
      if (l - 3 + k >= 0){
        float4 xv = *(const float4*)&xz[(size_t)(t0 + r + k - 3)*(2*DI_) + c];
        acc.x += xv.x*w0[k]; acc.y += xv.y*w1[k]; acc.z += xv.z*w2[k]; acc.w += xv.w*w3[k];
      }
    }
    acc.x = silu_f(acc.x); acc.y = silu_f(acc.y); acc.z = silu_f(acc.z); acc.w = silu_f(acc.w);
    *(float4*)&sxc[r*1024 + c] = acc;
    *(float4*)&xc[(size_t)(t0+r)*DI_ + c] = acc;
  }
  // P2: dbl[t][e] = sum_k sxc[t][k]*wxT[k][e]
  int lane = tid & 63, wv = tid >> 6;
  int ta = wv*2, tb = ta + 1;
  float acc0 = 0.f, acc1 = 0.f;
  __syncthreads();
  for (int k0 = 0; k0 < DI_; k0 += 64){
    #pragma unroll
    for (int i = tid; i < 1024; i += 256){
      int k = i >> 4, e4 = (i & 15)*4;
      float4 v = *(const float4*)&wxT[(size_t)(k0 + k)*64 + e4];
      swx[(e4+0)*68 + k] = v.x;
      swx[(e4+1)*68 + k] = v.y;
      swx[(e4+2)*68 + k] = v.z;
      swx[(e4+3)*68 + k] = v.w;
    }
    __syncthreads();
    #pragma unroll
    for (int k4 = 0; k4 < 64; k4 += 4){
      float4 wq = *(float4*)&swx[lane*68 + k4];
      float4 xa = *(float4*)&sxc[ta*1024 + k0 + k4];
      float4 xb = *(float4*)&sxc[tb*1024 + k0 + k4];
      acc0 += xa.x*wq.x + xa.y*wq.y + xa.z*wq.z + xa.w*wq.w;
      acc1 += xb.x*wq.x + xb.y*wq.y + xb.z*wq.z + xb.w*wq.w;
    }
    __syncthreads();
  }
  sdbl[ta][lane] = acc0;
  sdbl[tb][lane] = acc1;
  dblo[(size_t)(t0+ta)*64 + lane] = acc0;
  dblo[(size_t)(t0+tb)*64 + lane] = acc1;
  __syncthreads();
  // P3: delta = softplus(dt @ W_dt^T + b_dt)
  #pragma unroll
  for (int dc = 0; dc < 4; dc++){
    int d = dc*256 + tid;
    float wr[DTR_];
    #pragma unroll
    for (int r = 0; r < DTR_; r++) wr[r] = wdtT[(size_t)r*DI_ + d];
    float bb = bdt[d];
    #pragma unroll
    for (int t = 0; t < 8; t++){
      float acc = bb;
      #pragma unroll
      for (int r = 0; r < DTR_; r++) acc += sdbl[t][r]*wr[r];
      delta[(size_t)(t0+t)*DI_ + d] = softplus_f(acc);
    }
  }
}

// ---------------- chunked selective scan, d-per-lane ----------------
__global__ __launch_bounds__(256) void scan_part_kernel(const float* __restrict__ delta,
    const float* __restrict__ xc, const float* __restrict__ dbl,
    const float* __restrict__ Alog, float* __restrict__ hend, float* __restrict__ aprod){
  __shared__ float sBC[CL_][32];
  int tid = threadIdx.x;
  int d = blockIdx.x*256 + tid;
  int bych = blockIdx.y;               // b*NCH + ch
  int b = bych >> 4, ch = bych & (NCH_-1);
  int base = b*NP_ + ch*CL_;
  for (int i = tid; i < CL_*32; i += 256){
    int t = i >> 5, c = i & 31;
    sBC[t][c] = dbl[(size_t)(base+t)*64 + 32 + c];
  }
  float A[NS_], h[NS_], pr[NS_];
  #pragma unroll
  for (int k = 0; k < NS_; k++){
    A[k] = -__expf(Alog[(size_t)d*NS_ + k]);
    h[k] = 0.f; pr[k] = 1.f;
  }
  __syncthreads();
  #pragma unroll
  for (int t = 0; t < CL_; t++){
    int row = base + t;
    float de = delta[(size_t)row*DI_ + d];
    float xv = xc[(size_t)row*DI_ + d];
    float cde = de*xv;
    #pragma unroll
    for (int k = 0; k < NS_; k++){
      float a = __expf(de*A[k]);
      h[k] = a*h[k] + cde*sBC[t][k];
      pr[k] *= a;
    }
  }
  size_t o = ((size_t)bych*DI_ + d)*NS_;
  #pragma unroll
  for (int k = 0; k < NS_; k++){ hend[o+k] = h[k]; aprod[o+k] = pr[k]; }
}

__global__ __launch_bounds__(256) void scan_fix_kernel(const float* __restrict__ aprod,
    float* __restrict__ hend){
  int id = blockIdx.x*256 + threadIdx.x;  // over B*DI*NS = 131072
  int nd = id & (DI_*NS_ - 1);
  int b  = id >> 14;
  float h = 0.f;
  #pragma unroll
  for (int ch = 0; ch < NCH_; ch++){
    size_t idx = (size_t)(b*NCH_ + ch)*(DI_*NS_) + nd;
    float ap = aprod[idx];
    float he = hend[idx];
    hend[idx] = h;
    h = ap*h + he;
  }
}

__global__ __launch_bounds__(256) void scan_final_kernel(const float* __restrict__ delta,
    const float* __restrict__ xc, const float* __restrict__ dbl,
    const float* __restrict__ xz, const float* __restrict__ Dv,
    const float* __restrict__ Alog, const float* __restrict__ hin,
    u16* __restrict__ yb){
  __shared__ float sBC[CL_][32];
  int tid = threadIdx.x;
  int d = blockIdx.x*256 + tid;
  int bych = blockIdx.y;
  int b = bych >> 4, ch = bych & (NCH_-1);
  int base = b*NP_ + ch*CL_;
  for (int i = tid; i < CL_*32; i += 256){
    int t = i >> 5, c = i & 31;
    sBC[t][c] = dbl[(size_t)(base+t)*64 + 32 + c];
  }
  float A[NS_], h[NS_];
  size_t o = ((size_t)bych*DI_ + d)*NS_;
  #pragma unroll
  for (int k = 0; k < NS_; k++){
    A[k] = -__expf(Alog[(size_t)d*NS_ + k]);
    h[k] = hin[o + k];
  }
  float Dvd = Dv[d];
  __syncthreads();
  #pragma unroll
  for (int t = 0; t < CL_; t++){
    int row = base + t;
    float de = delta[(size_t)row*DI_ + d];
    float xv = xc[(size_t)row*DI_ + d];
    float zz = xz[(size_t)row*(2*DI_) + DI_ + d];
    float cde = de*xv;
    float p = 0.f;
    #pragma unroll
    for (int k = 0; k < NS_; k++){
      float a = __expf(de*A[k]);
      h[k] = a*h[k] + cde*sBC[t][k];
      p += h[k]*sBC[t][16+k];
    }
    yb[(size_t)row*DI_ + d] = f2bf((p + xv*Dvd) * silu_f(zz));
  }
}

// ---------------- head GEMM1: grid (16 nb, 128 kc), single-shot loads ----------------
__global__ __launch_bounds__(256) void head1_kernel(const float* __restrict__ u,
    const float* __restrict__ hW1, float* __restrict__ partial){
  const int KTOT = DM_*NP_;        // 131072
  int nb = blockIdx.x;             // 0..15 (8 n each)
  int kc = blockIdx.y;             // 0..127
  int tid = threadIdx.x;
  int lane = tid & 63, wv = tid >> 6;
  int k = kc*1024 + tid*4;
  float4 uv[8];
  #pragma unroll
  for (int m = 0; m < 8; m++) uv[m] = *(const float4*)&u[(size_t)m*KTOT + k];
  float acc[8][8];
  #pragma unroll
  for (int n = 0; n < 8; n++){
    float4 wv4 = *(const float4*)&hW1[(size_t)(nb*8+n)*KTOT + k];
    #pragma unroll
    for (int m = 0; m < 8; m++)
      acc[n][m] = uv[m].x*wv4.x + uv[m].y*wv4.y + uv[m].z*wv4.z + uv[m].w*wv4.w;
  }
  __shared__ float red[4][64];
  #pragma unroll
  for (int n = 0; n < 8; n++){
    #pragma unroll
    for (int m = 0; m < 8; m++){
      float v = acc[n][m];
      v += __shfl_xor(v,1); v += __shfl_xor(v,2); v += __shfl_xor(v,4);
      v += __shfl_xor(v,8); v += __shfl_xor(v,16); v += __shfl_xor(v,32);
      if (lane == 0) red[wv][n*8+m] = v;
    }
  }
  __syncthreads();
  if (tid < 64){
    float s = red[0][tid] + red[1][tid] + red[2][tid] + red[3][tid];
    int n = tid >> 3, m = tid & 7;
    partial[((size_t)kc*128 + nb*8 + n)*8 + m] = s;
  }
}

__global__ void head_combine_kernel(const float* __restrict__ partial,
    const float* __restrict__ hb1, float* __restrict__ t1){
  int idx = blockIdx.x*256 + threadIdx.x;  // n*8+m, 1024 total
  if (idx >= 128*8) return;
  int n = idx >> 3, m = idx & 7;
  float s = hb1[n];
  for (int kc = 0; kc < 128; kc++) s += partial[((size_t)kc*128 + n)*8 + m];
  float ge = 0.5f*s*(1.f + erff(s*0.70710678118f));
  t1[m*128 + n] = ge;
}

__global__ void head2_kernel(const float* __restrict__ t1, const float* __restrict__ hW2,
                             const float* __restrict__ hb2, float* __restrict__ out){
  int idx = blockIdx.x*128 + threadIdx.x;  // 8*96
  if (idx >= B_*PRED_) return;
  int m = idx / PRED_, q = idx % PRED_;
  float s = hb2[q];
  #pragma unroll 16
  for (int k = 0; k < 2*CD_; k++) s += t1[m*128 + k]*hW2[q*128 + k];
  out[idx] = s;
}

// ---------------- prep: vectorized bf16 conversions + transposes + peWb ----------------
__global__ __launch_bounds__(256) void prep_kernel(const float* __restrict__ W_dt,
    const float* __restrict__ W_x, const float* __restrict__ W_in,
    const float* __restrict__ W_out, const float* __restrict__ peW,
    float* __restrict__ wdtT, float* __restrict__ wxT,
    u16* __restrict__ WinB, u16* __restrict__ WoutB, u16* __restrict__ peWb){
  int idx = blockIdx.x*256 + threadIdx.x;   // 1,048,576 threads
  {
    float4 v = ((const float4*)W_in)[idx];
    ushort4 o = { f2bf(v.x), f2bf(v.y), f2bf(v.z), f2bf(v.w) };
    ((ushort4*)WinB)[idx] = o;
  }
  if (idx < 524288){
    float4 v = ((const float4*)W_out)[idx];
    ushort4 o = { f2bf(v.x), f2bf(v.y), f2bf(v.z), f2bf(v.w) };
    ((ushort4*)WoutB)[idx] = o;
  }
  if (idx < NL_*DTR_*DI_){
    int l = idx / (DTR_*DI_); int rem = idx % (DTR_*DI_);
    int r = rem / DI_; int d = rem % DI_;
    wdtT[idx] = W_dt[((size_t)l*DI_ + d)*DTR_ + r];
  }
  if (idx < NL_*DI_*64){
    int l = idx / (DI_*64); int rem = idx % (DI_*64);
    int kk = rem / 64; int e = rem % 64;
    wxT[idx] = W_x[((size_t)l*64 + e)*DI_ + kk];
  }
  if (idx < 512*128){
    int d = idx >> 7, kk = idx & 127;
    peWb[idx] = (kk < 112) ? f2bf(peW[d*112 + kk]) : (u16)0;
  }
}

extern "C" void kernel_launch(void* const* d_in, const int* in_sizes, int n_in,
                              void* d_out, int out_size, void* d_ws, size_t ws_size,
                              hipStream_t stream) {
  const float* x      = (const float*)d_in[0];
  const float* in_g   = (const float*)d_in[1];
  const float* in_b   = (const float*)d_in[2];
  const float* pe_W   = (const float*)d_in[3];
  const float* pe_b   = (const float*)d_in[4];
  const float* ln_g   = (const float*)d_in[5];
  const float* ln_b   = (const float*)d_in[6];
  const float* W_in   = (const float*)d_in[7];
  const float* conv_W = (const float*)d_in[8];
  const float* conv_b = (const float*)d_in[9];
  const float* W_x    = (const float*)d_in[10];
  const float* W_dt   = (const float*)d_in[11];
  const float* b_dt   = (const float*)d_in[12];
  const float* A_log  = (const float*)d_in[13];
  const float* Dskip  = (const float*)d_in[14];
  const float* W_out  = (const float*)d_in[15];
  const float* fn_g   = (const float*)d_in[16];
  const float* fn_b   = (const float*)d_in[17];
  const float* hW1    = (const float*)d_in[18];
  const float* hb1    = (const float*)d_in[19];
  const float* hW2    = (const float*)d_in[20];
  const float* hb2    = (const float*)d_in[21];

  float* ws    = (float*)d_ws;
  float* h     = ws;                    // 1,048,576 f
  float* un    = h     + 1048576;       // 1,048,576 f
  float* xz    = un    + 1048576;       // 4,194,304 f
  float* xc    = xz    + 4194304;       // 2,097,152 f
  float* dblb  = xc    + 2097152;       //   131,072 f
  float* delta = dblb  + 131072;        // 2,097,152 f
  float* y     = delta + 2097152;       // 2,097,152 f   (reused: hend/hin; prologue xpb)
  float* wdtT  = y     + 2097152;       //   131,072 f
  float* wxT   = wdtT  + 131072;        //   262,144 f
  float* bf_rgn= wxT   + 262144;
  u16*   unb   = (u16*)bf_rgn;                  // 1,048,576 u16
  u16*   yb    = (u16*)(bf_rgn + 524288);       // 2,097,152 u16
  u16*   WinB  = (u16*)(bf_rgn + 524288 + 1048576);            // 4,194,304 u16
  u16*   WoutB = (u16*)(bf_rgn + 524288 + 1048576 + 2097152);  // 2,097,152 u16
  u16*   peWb  = (u16*)(bf_rgn + 524288 + 1048576 + 2097152 + 1048576); // 65,536 u16
  float* aprod = bf_rgn + 524288 + 1048576 + 2097152 + 1048576 + 32768; // 2,097,152 f
  float* hend  = y;                     // [B*NCH][DI][NS]; becomes hin after pass B
  u16*   xpb   = (u16*)y;               // prologue-only: bf16 patches [2048][128]
  float* partial = xz;                  // epilogue-only (128*128*8 = 131072 f)
  float* t1      = xz + 262144;

  prep_kernel<<<4096, 256, 0, stream>>>(W_dt, W_x, W_in, W_out, pe_W,
                                        wdtT, wxT, WinB, WoutB, peWb);
  ln7_kernel<<<(B_*SEQ_+255)/256, 256, 0, stream>>>(x, in_g, in_b, xpb);
  // patch-embed as bf16 GEMM: h[2048][512] = xpb[2048][128] @ peWb[512][128]^T + pe_b
  gemm_bf16<64,128,false,true><<<dim3(DM_/128, TOK_/64), 256, 0, stream>>>(
      xpb, peWb, h, pe_b, 128, 128, 128, DM_);

  for (int l = 0; l < NL_; l++){
    ln512_kernel<<<TOK_/4, 256, 0, stream>>>(h, ln_g + l*DM_, ln_b + l*DM_, un, unb);
    gemm_bf16<64,128,false,false><<<dim3(2*DI_/128, TOK_/64), 256, 0, stream>>>(
        unb, WinB + (size_t)l*2*DI_*DM_, xz, nullptr, DM_, DM_, DM_, 2*DI_);
    mid_kernel<<<TOK_/8, 256, 0, stream>>>(
        xz, conv_W + (size_t)l*DI_*DC_, conv_b + (size_t)l*DI_,
        wxT + (size_t)l*DI_*64, wdtT + (size_t)l*DTR_*DI_, b_dt + (size_t)l*DI_,
        xc, dblb, delta);
    scan_part_kernel<<<dim3(DI_/256, B_*NCH_), 256, 0, stream>>>(
        delta, xc, dblb, A_log + (size_t)l*DI_*NS_, hend, aprod);
    scan_fix_kernel<<<(B_*DI_*NS_)/256, 256, 0, stream>>>(aprod, hend);
    scan_final_kernel<<<dim3(DI_/256, B_*NCH_), 256, 0, stream>>>(
        delta, xc, dblb, xz, Dskip + (size_t)l*DI_, A_log + (size_t)l*DI_*NS_, hend, yb);
    gemm_bf16<64,64,true,false><<<dim3(DM_/64, TOK_/64), 256, 0, stream>>>(
        yb, WoutB + (size_t)l*DM_*DI_, h, nullptr, DI_, DI_, DI_, DM_);
  }

  ln512_kernel<<<TOK_/4, 256, 0, stream>>>(h, fn_g, fn_b, un, unb);
  head1_kernel<<<dim3(16, 128), 256, 0, stream>>>(un, hW1, partial);
  head_combine_kernel<<<4, 256, 0, stream>>>(partial, hb1, t1);
  head2_kernel<<<6, 128, 0, stream>>>(t1, hW2, hb2, (float*)d_out);
}

// Round 7
// 603.404 us; speedup vs baseline: 1.3320x; 1.1131x over previous
//
#include <hip/hip_runtime.h>
#include <hip/hip_bf16.h>
#include <math.h>

#define B_    8
#define SEQ_  4096
#define CIN_  7
#define DM_   512
#define NL_   4
#define PL_   16
#define NP_   256
#define NS_   16
#define DC_   4
#define DI_   1024
#define DTR_  32
#define CD_   64
#define PRED_ 96
#define TOK_  (B_*NP_)   // 2048
#define EPS_  1e-5f
#define CL_   16         // scan chunk length
#define NCH_  (NP_/CL_)  // 16 chunks

typedef unsigned short u16;
typedef __attribute__((ext_vector_type(8))) short short8;
typedef __attribute__((ext_vector_type(4))) float floatx4;

__device__ __forceinline__ float silu_f(float x){ return x / (1.f + __expf(-x)); }
__device__ __forceinline__ float softplus_f(float x){ return x > 20.f ? x : log1pf(__expf(x)); }
__device__ __forceinline__ u16 f2bf(float f){
  union { __hip_bfloat16 h; u16 u; } cv; cv.h = __float2bfloat16(f); return cv.u;
}
#define GLDS16(g, l) __builtin_amdgcn_global_load_lds( \
    (const __attribute__((address_space(1))) void*)(g), \
    (__attribute__((address_space(3))) void*)(l), 16, 0, 0)

// ---------------- LN over CIN=7 -> bf16 patch rows [2048][128] (zero-padded 112..127) ----------------
__global__ void ln7_kernel(const float* __restrict__ x, const float* __restrict__ g,
                           const float* __restrict__ b, u16* __restrict__ xpb){
  int i = blockIdx.x*256 + threadIdx.x; // over B*SEQ
  if (i >= B_*SEQ_) return;
  float v[CIN_]; float m = 0.f;
  #pragma unroll
  for (int c=0;c<CIN_;c++){ v[c]=x[i*CIN_+c]; m+=v[c]; }
  m *= (1.f/CIN_);
  float var = 0.f;
  #pragma unroll
  for (int c=0;c<CIN_;c++){ float d=v[c]-m; var+=d*d; }
  var *= (1.f/CIN_);
  float r = rsqrtf(var + EPS_);
  int bn = i >> 4, p = i & 15;            // token, pos-in-patch
  u16* row = xpb + (size_t)bn*128;
  #pragma unroll
  for (int c=0;c<CIN_;c++) row[c*16+p] = f2bf((v[c]-m)*r*g[c]+b[c]);
  row[112+p] = 0;
}

// ---------------- LN over DM=512, wave-per-token, fp32+bf16 out ----------------
__global__ __launch_bounds__(256) void ln512_kernel(const float* __restrict__ in,
    const float* __restrict__ g, const float* __restrict__ b,
    float* __restrict__ out, u16* __restrict__ outb){
  int tid = threadIdx.x;
  int wv = tid>>6, lane = tid&63;
  int t = blockIdx.x*4 + wv;
  const float4* row = (const float4*)(in + (size_t)t*DM_);
  float4 v0 = row[lane], v1 = row[64+lane];
  float s = v0.x+v0.y+v0.z+v0.w + v1.x+v1.y+v1.z+v1.w;
  #pragma unroll
  for (int o=1;o<64;o<<=1) s += __shfl_xor(s,o);
  float m = s*(1.f/DM_);
  float d0x=v0.x-m,d0y=v0.y-m,d0z=v0.z-m,d0w=v0.w-m;
  float d1x=v1.x-m,d1y=v1.y-m,d1z=v1.z-m,d1w=v1.w-m;
  float q = d0x*d0x+d0y*d0y+d0z*d0z+d0w*d0w + d1x*d1x+d1y*d1y+d1z*d1z+d1w*d1w;
  #pragma unroll
  for (int o=1;o<64;o<<=1) q += __shfl_xor(q,o);
  float r = rsqrtf(q*(1.f/DM_) + EPS_);
  float4 g0 = ((const float4*)g)[lane], g1 = ((const float4*)g)[64+lane];
  float4 b0 = ((const float4*)b)[lane], b1 = ((const float4*)b)[64+lane];
  float4 o0 = { d0x*r*g0.x+b0.x, d0y*r*g0.y+b0.y, d0z*r*g0.z+b0.z, d0w*r*g0.w+b0.w };
  float4 o1 = { d1x*r*g1.x+b1.x, d1y*r*g1.y+b1.y, d1z*r*g1.z+b1.z, d1w*r*g1.w+b1.w };
  ((float4*)(out + (size_t)t*DM_))[lane]    = o0;
  ((float4*)(out + (size_t)t*DM_))[64+lane] = o1;
  ushort4 p0 = { f2bf(o0.x), f2bf(o0.y), f2bf(o0.z), f2bf(o0.w) };
  ushort4 p1 = { f2bf(o1.x), f2bf(o1.y), f2bf(o1.z), f2bf(o1.w) };
  ((ushort4*)(outb + (size_t)t*DM_))[lane]    = p0;
  ((ushort4*)(outb + (size_t)t*DM_))[64+lane] = p1;
}

// ---------------- bf16 MFMA NT GEMM: C[M,N](f32) = A[M,K]*B[N,K]^T (+bias) ----------------
template<int BM, int BN, bool ACC, bool BIAS>
__global__ __launch_bounds__(256) void gemm_bf16(const u16* __restrict__ A,
    const u16* __restrict__ Bw, float* __restrict__ C, const float* __restrict__ bias,
    int K, int lda, int ldb, int ldc){
  constexpr int MI = BM/32, NI = BN/32;
  __shared__ __align__(16) u16 As[BM*64];
  __shared__ __align__(16) u16 Bs[BN*64];
  int tid = threadIdx.x;
  int wave = __builtin_amdgcn_readfirstlane(tid>>6);
  int lane = tid&63;
  int wm = wave>>1, wn = wave&1;
  int quad = lane>>4, l16 = lane&15;
  int bm = blockIdx.y*BM, bn = blockIdx.x*BN;
  int r8 = lane>>3, sseg = lane&7;
  int gseg = sseg ^ r8;                  // global k-seg this lane fetches
  floatx4 acc[MI][NI] = {};
  for (int k0 = 0; k0 < K; k0 += 64){
    #pragma unroll
    for (int r = 0; r < BM/32; r++){
      int rowb = (r*4 + wave)*8;
      const u16* gp = A + (size_t)(bm + rowb + r8)*lda + k0 + gseg*8;
      GLDS16(gp, &As[rowb*64]);
    }
    #pragma unroll
    for (int r = 0; r < BN/32; r++){
      int rowb = (r*4 + wave)*8;
      const u16* gp = Bw + (size_t)(bn + rowb + r8)*ldb + k0 + gseg*8;
      GLDS16(gp, &Bs[rowb*64]);
    }
    __syncthreads();
    #pragma unroll
    for (int kh = 0; kh < 2; kh++){
      short8 af[MI], bfr[NI];
      #pragma unroll
      for (int i = 0; i < MI; i++){
        int row = wm*(BM/2)+i*16+l16;
        af[i] = *(short8*)&As[row*64 + (((kh*4+quad)^(row&7))*8)];
      }
      #pragma unroll
      for (int j = 0; j < NI; j++){
        int row = wn*(BN/2)+j*16+l16;
        bfr[j] = *(short8*)&Bs[row*64 + (((kh*4+quad)^(row&7))*8)];
      }
      #pragma unroll
      for (int i = 0; i < MI; i++)
        #pragma unroll
        for (int j = 0; j < NI; j++)
          acc[i][j] = __builtin_amdgcn_mfma_f32_16x16x32_bf16(af[i], bfr[j], acc[i][j], 0, 0, 0);
    }
    __syncthreads();
  }
  #pragma unroll
  for (int i = 0; i < MI; i++){
    #pragma unroll
    for (int j = 0; j < NI; j++){
      #pragma unroll
      for (int r = 0; r < 4; r++){
        int m  = bm + wm*(BM/2) + i*16 + quad*4 + r;
        int nn = bn + wn*(BN/2) + j*16 + l16;
        float v = acc[i][j][r];
        if (ACC) C[(size_t)m*ldc+nn] += v;
        else     C[(size_t)m*ldc+nn]  = BIAS ? v + bias[nn] : v;
      }
    }
  }
}

// ---------------- causal depthwise conv (DC=4) + bias + silu -> xc fp32 + xcb bf16 ----------------
__global__ void conv_silu_kernel(const float* __restrict__ xz, const float* __restrict__ cW,
                                 const float* __restrict__ cb, float* __restrict__ xc,
                                 u16* __restrict__ xcb){
  int idx = blockIdx.x*256 + threadIdx.x;   // over TOK*DI/4
  if (idx >= TOK_*DI_/4) return;
  int c4 = idx & (DI_/4 - 1); int t = idx >> 8;
  int l = t & (NP_-1);
  int c = c4*4;
  float4 acc = *(const float4*)&cb[c];
  float wa[4], wb[4], wc[4], wd[4];
  *(float4*)wa = *(const float4*)&cW[(c+0)*DC_];
  *(float4*)wb = *(const float4*)&cW[(c+1)*DC_];
  *(float4*)wc = *(const float4*)&cW[(c+2)*DC_];
  *(float4*)wd = *(const float4*)&cW[(c+3)*DC_];
  const float* base = xz + (size_t)t*(2*DI_) + c;
  #pragma unroll
  for (int k = 0; k < DC_; k++){
    if (l - 3 + k >= 0){
      float4 xv = *(const float4*)(base + (k-3)*(2*DI_));
      acc.x += xv.x*wa[k];
      acc.y += xv.y*wb[k];
      acc.z += xv.z*wc[k];
      acc.w += xv.w*wd[k];
    }
  }
  acc.x = silu_f(acc.x); acc.y = silu_f(acc.y);
  acc.z = silu_f(acc.z); acc.w = silu_f(acc.w);
  *(float4*)&xc[(size_t)t*DI_ + c] = acc;
  ushort4 pb = { f2bf(acc.x), f2bf(acc.y), f2bf(acc.z), f2bf(acc.w) };
  *(ushort4*)&xcb[(size_t)t*DI_ + c] = pb;
}

// ---------------- delta = softplus(dt @ W_dt^T + b_dt), 16 t per block ----------------
__global__ __launch_bounds__(256) void delta_kernel(const float* __restrict__ dbl,
    const float* __restrict__ wdtT, const float* __restrict__ bdt, float* __restrict__ delta){
  __shared__ float sdt[16][DTR_];
  int tid = threadIdx.x;
  int t0 = blockIdx.y*16;
  int d = blockIdx.x*256 + tid;
  for (int i = tid; i < 16*DTR_; i += 256){
    int t = i >> 5, r = i & 31;
    sdt[t][r] = dbl[(size_t)(t0 + t)*64 + r];
  }
  float wv[DTR_];
  #pragma unroll
  for (int r = 0; r < DTR_; r++) wv[r] = wdtT[(size_t)r*DI_ + d];
  float bb = bdt[d];
  __syncthreads();
  #pragma unroll 4
  for (int t = 0; t < 16; t++){
    float acc = bb;
    #pragma unroll
    for (int r = 0; r < DTR_; r++) acc += sdt[t][r]*wv[r];
    delta[(size_t)(t0 + t)*DI_ + d] = softplus_f(acc);
  }
}

// ---------------- chunked selective scan, d-per-lane ----------------
__global__ __launch_bounds__(256) void scan_part_kernel(const float* __restrict__ delta,
    const float* __restrict__ xc, const float* __restrict__ dbl,
    const float* __restrict__ Alog, float* __restrict__ hend, float* __restrict__ aprod){
  __shared__ float sBC[CL_][32];
  int tid = threadIdx.x;
  int d = blockIdx.x*256 + tid;
  int bych = blockIdx.y;               // b*NCH + ch
  int b = bych >> 4, ch = bych & (NCH_-1);
  int base = b*NP_ + ch*CL_;
  for (int i = tid; i < CL_*32; i += 256){
    int t = i >> 5, c = i & 31;
    sBC[t][c] = dbl[(size_t)(base+t)*64 + 32 + c];
  }
  float A[NS_], h[NS_], pr[NS_];
  #pragma unroll
  for (int k = 0; k < NS_; k++){
    A[k] = -__expf(Alog[(size_t)d*NS_ + k]);
    h[k] = 0.f; pr[k] = 1.f;
  }
  __syncthreads();
  #pragma unroll
  for (int t = 0; t < CL_; t++){
    int row = base + t;
    float de = delta[(size_t)row*DI_ + d];
    float xv = xc[(size_t)row*DI_ + d];
    float cde = de*xv;
    #pragma unroll
    for (int k = 0; k < NS_; k++){
      float a = __expf(de*A[k]);
      h[k] = a*h[k] + cde*sBC[t][k];
      pr[k] *= a;
    }
  }
  size_t o = ((size_t)bych*DI_ + d)*NS_;
  #pragma unroll
  for (int k = 0; k < NS_; k++){ hend[o+k] = h[k]; aprod[o+k] = pr[k]; }
}

__global__ __launch_bounds__(256) void scan_fix_kernel(const float* __restrict__ aprod,
    float* __restrict__ hend){
  int id = blockIdx.x*256 + threadIdx.x;  // over B*DI*NS = 131072
  int nd = id & (DI_*NS_ - 1);
  int b  = id >> 14;
  float h = 0.f;
  #pragma unroll
  for (int ch = 0; ch < NCH_; ch++){
    size_t idx = (size_t)(b*NCH_ + ch)*(DI_*NS_) + nd;
    float ap = aprod[idx];
    float he = hend[idx];
    hend[idx] = h;
    h = ap*h + he;
  }
}

__global__ __launch_bounds__(256) void scan_final_kernel(const float* __restrict__ delta,
    const float* __restrict__ xc, const float* __restrict__ dbl,
    const float* __restrict__ xz, const float* __restrict__ Dv,
    const float* __restrict__ Alog, const float* __restrict__ hin,
    u16* __restrict__ yb){
  __shared__ float sBC[CL_][32];
  int tid = threadIdx.x;
  int d = blockIdx.x*256 + tid;
  int bych = blockIdx.y;
  int b = bych >> 4, ch = bych & (NCH_-1);
  int base = b*NP_ + ch*CL_;
  for (int i = tid; i < CL_*32; i += 256){
    int t = i >> 5, c = i & 31;
    sBC[t][c] = dbl[(size_t)(base+t)*64 + 32 + c];
  }
  float A[NS_], h[NS_];
  size_t o = ((size_t)bych*DI_ + d)*NS_;
  #pragma unroll
  for (int k = 0; k < NS_; k++){
    A[k] = -__expf(Alog[(size_t)d*NS_ + k]);
    h[k] = hin[o + k];
  }
  float Dvd = Dv[d];
  __syncthreads();
  #pragma unroll
  for (int t = 0; t < CL_; t++){
    int row = base + t;
    float de = delta[(size_t)row*DI_ + d];
    float xv = xc[(size_t)row*DI_ + d];
    float zz = xz[(size_t)row*(2*DI_) + DI_ + d];
    float cde = de*xv;
    float p = 0.f;
    #pragma unroll
    for (int k = 0; k < NS_; k++){
      float a = __expf(de*A[k]);
      h[k] = a*h[k] + cde*sBC[t][k];
      p += h[k]*sBC[t][16+k];
    }
    yb[(size_t)row*DI_ + d] = f2bf((p + xv*Dvd) * silu_f(zz));
  }
}

// ---------------- head GEMM1: grid (16 nb, 128 kc), single-shot loads ----------------
__global__ __launch_bounds__(256) void head1_kernel(const float* __restrict__ u,
    const float* __restrict__ hW1, float* __restrict__ partial){
  const int KTOT = DM_*NP_;        // 131072
  int nb = blockIdx.x;             // 0..15 (8 n each)
  int kc = blockIdx.y;             // 0..127
  int tid = threadIdx.x;
  int lane = tid & 63, wv = tid >> 6;
  int k = kc*1024 + tid*4;
  float4 uv[8];
  #pragma unroll
  for (int m = 0; m < 8; m++) uv[m] = *(const float4*)&u[(size_t)m*KTOT + k];
  float acc[8][8];
  #pragma unroll
  for (int n = 0; n < 8; n++){
    float4 wv4 = *(const float4*)&hW1[(size_t)(nb*8+n)*KTOT + k];
    #pragma unroll
    for (int m = 0; m < 8; m++)
      acc[n][m] = uv[m].x*wv4.x + uv[m].y*wv4.y + uv[m].z*wv4.z + uv[m].w*wv4.w;
  }
  __shared__ float red[4][64];
  #pragma unroll
  for (int n = 0; n < 8; n++){
    #pragma unroll
    for (int m = 0; m < 8; m++){
      float v = acc[n][m];
      v += __shfl_xor(v,1); v += __shfl_xor(v,2); v += __shfl_xor(v,4);
      v += __shfl_xor(v,8); v += __shfl_xor(v,16); v += __shfl_xor(v,32);
      if (lane == 0) red[wv][n*8+m] = v;
    }
  }
  __syncthreads();
  if (tid < 64){
    float s = red[0][tid] + red[1][tid] + red[2][tid] + red[3][tid];
    int n = tid >> 3, m = tid & 7;
    partial[((size_t)kc*128 + nb*8 + n)*8 + m] = s;
  }
}

__global__ void head_combine_kernel(const float* __restrict__ partial,
    const float* __restrict__ hb1, float* __restrict__ t1){
  int idx = blockIdx.x*256 + threadIdx.x;  // n*8+m, 1024 total
  if (idx >= 128*8) return;
  int n = idx >> 3, m = idx & 7;
  float s = hb1[n];
  for (int kc = 0; kc < 128; kc++) s += partial[((size_t)kc*128 + n)*8 + m];
  float ge = 0.5f*s*(1.f + erff(s*0.70710678118f));
  t1[m*128 + n] = ge;
}

__global__ void head2_kernel(const float* __restrict__ t1, const float* __restrict__ hW2,
                             const float* __restrict__ hb2, float* __restrict__ out){
  int idx = blockIdx.x*128 + threadIdx.x;  // 8*96
  if (idx >= B_*PRED_) return;
  int m = idx / PRED_, q = idx % PRED_;
  float s = hb2[q];
  #pragma unroll 16
  for (int k = 0; k < 2*CD_; k++) s += t1[m*128 + k]*hW2[q*128 + k];
  out[idx] = s;
}

// ---------------- prep: vectorized bf16 conversions + transposes ----------------
__global__ __launch_bounds__(256) void prep_kernel(const float* __restrict__ W_dt,
    const float* __restrict__ W_x, const float* __restrict__ W_in,
    const float* __restrict__ W_out, const float* __restrict__ peW,
    float* __restrict__ wdtT, u16* __restrict__ wxB,
    u16* __restrict__ WinB, u16* __restrict__ WoutB, u16* __restrict__ peWb){
  int idx = blockIdx.x*256 + threadIdx.x;   // 1,048,576 threads
  {
    float4 v = ((const float4*)W_in)[idx];
    ushort4 o = { f2bf(v.x), f2bf(v.y), f2bf(v.z), f2bf(v.w) };
    ((ushort4*)WinB)[idx] = o;
  }
  if (idx < 524288){
    float4 v = ((const float4*)W_out)[idx];
    ushort4 o = { f2bf(v.x), f2bf(v.y), f2bf(v.z), f2bf(v.w) };
    ((ushort4*)WoutB)[idx] = o;
  }
  if (idx < NL_*64*DI_/4){   // wxB: straight bf16 copy of W_x (NT layout already)
    float4 v = ((const float4*)W_x)[idx];
    ushort4 o = { f2bf(v.x), f2bf(v.y), f2bf(v.z), f2bf(v.w) };
    ((ushort4*)wxB)[idx] = o;
  }
  if (idx < NL_*DTR_*DI_){
    int l = idx / (DTR_*DI_); int rem = idx % (DTR_*DI_);
    int r = rem / DI_; int d = rem % DI_;
    wdtT[idx] = W_dt[((size_t)l*DI_ + d)*DTR_ + r];
  }
  if (idx < 512*128){
    int d = idx >> 7, kk = idx & 127;
    peWb[idx] = (kk < 112) ? f2bf(peW[d*112 + kk]) : (u16)0;
  }
}

extern "C" void kernel_launch(void* const* d_in, const int* in_sizes, int n_in,
                              void* d_out, int out_size, void* d_ws, size_t ws_size,
                              hipStream_t stream) {
  const float* x      = (const float*)d_in[0];
  const float* in_g   = (const float*)d_in[1];
  const float* in_b   = (const float*)d_in[2];
  const float* pe_W   = (const float*)d_in[3];
  const float* pe_b   = (const float*)d_in[4];
  const float* ln_g   = (const float*)d_in[5];
  const float* ln_b   = (const float*)d_in[6];
  const float* W_in   = (const float*)d_in[7];
  const float* conv_W = (const float*)d_in[8];
  const float* conv_b = (const float*)d_in[9];
  const float* W_x    = (const float*)d_in[10];
  const float* W_dt   = (const float*)d_in[11];
  const float* b_dt   = (const float*)d_in[12];
  const float* A_log  = (const float*)d_in[13];
  const float* Dskip  = (const float*)d_in[14];
  const float* W_out  = (const float*)d_in[15];
  const float* fn_g   = (const float*)d_in[16];
  const float* fn_b   = (const float*)d_in[17];
  const float* hW1    = (const float*)d_in[18];
  const float* hb1    = (const float*)d_in[19];
  const float* hW2    = (const float*)d_in[20];
  const float* hb2    = (const float*)d_in[21];

  float* ws    = (float*)d_ws;
  float* h     = ws;                    // 1,048,576 f
  float* un    = h     + 1048576;       // 1,048,576 f
  float* xz    = un    + 1048576;       // 4,194,304 f
  float* xc    = xz    + 4194304;       // 2,097,152 f
  float* dblb  = xc    + 2097152;       //   131,072 f
  float* delta = dblb  + 131072;        // 2,097,152 f
  float* y     = delta + 2097152;       // 2,097,152 f  (overlays: xpb prologue, xcb conv, hend scan)
  float* wdtT  = y     + 2097152;       //   131,072 f
  u16*   wxB   = (u16*)(wdtT + 131072);         //   262,144 u16 (=131,072 f)
  float* bf_rgn= wdtT + 131072 + 131072;
  u16*   unb   = (u16*)bf_rgn;                  // 1,048,576 u16
  u16*   yb    = (u16*)(bf_rgn + 524288);       // 2,097,152 u16
  u16*   WinB  = (u16*)(bf_rgn + 524288 + 1048576);            // 4,194,304 u16
  u16*   WoutB = (u16*)(bf_rgn + 524288 + 1048576 + 2097152);  // 2,097,152 u16
  u16*   peWb  = (u16*)(bf_rgn + 524288 + 1048576 + 2097152 + 1048576); // 65,536 u16
  float* aprod = bf_rgn + 524288 + 1048576 + 2097152 + 1048576 + 32768; // 2,097,152 f
  // end ≈ 79.3 MB
  float* hend  = y;                     // [B*NCH][DI][NS]; becomes hin after pass B
  u16*   xcb   = (u16*)y;               // bf16 xc [2048][1024]; free before scan_part
  u16*   xpb   = (u16*)y;               // prologue-only: bf16 patches [2048][128]
  float* partial = xz;                  // epilogue-only (128*128*8 = 131072 f)
  float* t1      = xz + 262144;

  prep_kernel<<<4096, 256, 0, stream>>>(W_dt, W_x, W_in, W_out, pe_W,
                                        wdtT, wxB, WinB, WoutB, peWb);
  ln7_kernel<<<(B_*SEQ_+255)/256, 256, 0, stream>>>(x, in_g, in_b, xpb);
  // patch-embed as bf16 GEMM: h[2048][512] = xpb[2048][128] @ peWb[512][128]^T + pe_b
  gemm_bf16<64,128,false,true><<<dim3(DM_/128, TOK_/64), 256, 0, stream>>>(
      xpb, peWb, h, pe_b, 128, 128, 128, DM_);

  for (int l = 0; l < NL_; l++){
    ln512_kernel<<<TOK_/4, 256, 0, stream>>>(h, ln_g + l*DM_, ln_b + l*DM_, un, unb);
    gemm_bf16<64,128,false,false><<<dim3(2*DI_/128, TOK_/64), 256, 0, stream>>>(
        unb, WinB + (size_t)l*2*DI_*DM_, xz, nullptr, DM_, DM_, DM_, 2*DI_);
    conv_silu_kernel<<<(TOK_*DI_/4)/256, 256, 0, stream>>>(
        xz, conv_W + (size_t)l*DI_*DC_, conv_b + (size_t)l*DI_, xc, xcb);
    // dbl[2048][64] = xcb[2048][1024] @ W_x[64][1024]^T   (bf16 MFMA)
    gemm_bf16<64,64,false,false><<<dim3(1, TOK_/64), 256, 0, stream>>>(
        xcb, wxB + (size_t)l*64*DI_, dblb, nullptr, DI_, DI_, DI_, 64);
    delta_kernel<<<dim3(DI_/256, TOK_/16), 256, 0, stream>>>(
        dblb, wdtT + (size_t)l*DTR_*DI_, b_dt + (size_t)l*DI_, delta);
    scan_part_kernel<<<dim3(DI_/256, B_*NCH_), 256, 0, stream>>>(
        delta, xc, dblb, A_log + (size_t)l*DI_*NS_, hend, aprod);
    scan_fix_kernel<<<(B_*DI_*NS_)/256, 256, 0, stream>>>(aprod, hend);
    scan_final_kernel<<<dim3(DI_/256, B_*NCH_), 256, 0, stream>>>(
        delta, xc, dblb, xz, Dskip + (size_t)l*DI_, A_log + (size_t)l*DI_*NS_, hend, yb);
    gemm_bf16<64,64,true,false><<<dim3(DM_/64, TOK_/64), 256, 0, stream>>>(
        yb, WoutB + (size_t)l*DM_*DI_, h, nullptr, DI_, DI_, DI_, DM_);
  }

  ln512_kernel<<<TOK_/4, 256, 0, stream>>>(h, fn_g, fn_b, un, unb);
  head1_kernel<<<dim3(16, 128), 256, 0, stream>>>(un, hW1, partial);
  head_combine_kernel<<<4, 256, 0, stream>>>(partial, hb1, t1);
  head2_kernel<<<6, 128, 0, stream>>>(t1, hW2, hb2, (float*)d_out);
}